// Round 21
// baseline (272.613 us; speedup 1.0000x reference)
//
#include <hip/hip_runtime.h>
#include <hip/hip_fp16.h>

#define DIM 128
#define CSTRIDE 64
#define BSHIFT 9
#define MAXBE 9216
typedef _Float16 half8 __attribute__((ext_vector_type(8)));
typedef float f32x4 __attribute__((ext_vector_type(4)));

// ---- pack W1,W2[0:128] into MFMA B-fragments; 16 blocks (8 per matrix) ----
__global__ void k_wprep(const float* __restrict__ W1, const float* __restrict__ W2,
                        __half* __restrict__ Wf1h, __half* __restrict__ Wf2h,
                        int* __restrict__ bucketCur){
  const float* Wsrc = (blockIdx.x < 8) ? W1 : W2;
  _Float16* Wf = (_Float16*)((blockIdx.x < 8) ? Wf1h : Wf2h);
  int id   = (blockIdx.x & 7)*256 + threadIdx.x; // (ct*4+kc)*64 + lane
  int lane = id & 63;
  int ckc  = id >> 6;
  int kc   = ckc & 3, ct = ckc >> 2;
  int kbase = kc*32 + (lane >> 4)*8;
  int c     = ct*16 + (lane & 15);
  half8 v;
  #pragma unroll
  for (int i = 0; i < 8; i++)
    v[i] = (_Float16)Wsrc[(size_t)(kbase + i)*DIM + c];
  *(half8*)(Wf + (size_t)id*8) = v;
  if (blockIdx.x == 0) bucketCur[threadIdx.x] = 0;
}

// ---- MFMA GEMM tile: Yh[64 rows](f16) = scale * ((relu?)X @ W + addvec) ----
template<int INH>
__device__ __forceinline__ void gemm_mfma(const void* __restrict__ Xv,
    const _Float16* __restrict__ Wf, const float* __restrict__ addvec,
    const int* __restrict__ cntp, __half* __restrict__ Yh, int N, int doRelu, int gb){
  int wid = threadIdx.x >> 6;
  int l   = threadIdx.x & 63;
  int g   = l >> 4;
  int lr  = l & 15;
  int rowA = gb*64 + wid*16 + lr;
  int rA   = (rowA < N) ? rowA : (N - 1);

  f32x4 acc[8];
  #pragma unroll
  for (int ct = 0; ct < 8; ct++) acc[ct] = (f32x4){0.f, 0.f, 0.f, 0.f};

  #pragma unroll
  for (int kc = 0; kc < 4; kc++){
    half8 a;
    if (INH){
      a = *(const half8*)((const _Float16*)Xv + (size_t)rA*DIM + kc*32 + g*8);
    } else {
      const float* xp = (const float*)Xv + (size_t)rA*DIM + kc*32 + g*8;
      float4 x0 = *(const float4*)xp;
      float4 x1 = *(const float4*)(xp + 4);
      a[0]=(_Float16)x0.x; a[1]=(_Float16)x0.y; a[2]=(_Float16)x0.z; a[3]=(_Float16)x0.w;
      a[4]=(_Float16)x1.x; a[5]=(_Float16)x1.y; a[6]=(_Float16)x1.z; a[7]=(_Float16)x1.w;
    }
    if (doRelu){
      #pragma unroll
      for (int i = 0; i < 8; i++) a[i] = (a[i] > (_Float16)0.f) ? a[i] : (_Float16)0.f;
    }
    #pragma unroll
    for (int ct = 0; ct < 8; ct++){
      half8 b = *(const half8*)(Wf + ((size_t)(ct*4 + kc)*64 + l)*8);
      acc[ct] = __builtin_amdgcn_mfma_f32_16x16x32_f16(a, b, acc[ct], 0, 0, 0);
    }
  }

  // C/D layout (HW-verified): col = lane&15, row = (lane>>4)*4 + reg
  int m0 = gb*64 + wid*16 + g*4;
  float av[8];
  #pragma unroll
  for (int ct = 0; ct < 8; ct++) av[ct] = addvec ? addvec[ct*16 + lr] : 0.f;
  #pragma unroll
  for (int r = 0; r < 4; r++){
    int rr = m0 + r;
    if (rr < N){
      float dv = cntp ? rsqrtf((float)(cntp[rr] + 1)) : 1.f;
      #pragma unroll
      for (int ct = 0; ct < 8; ct++){
        float o = dv*(acc[ct][r] + av[ct]);
        Yh[(size_t)rr*DIM + ct*16 + lr] = __float2half(o);
      }
    }
  }
}

// ---- megaB: per 3 blocks, 2 = gemm1 (unscaled), 1 = LDS-aggregated bucket scatter ----
__global__ __launch_bounds__(256) void k_megaB(const float* __restrict__ posts,
    const __half* __restrict__ Wf1, __half* __restrict__ xw1u,
    const int* __restrict__ row, const int* __restrict__ col, int E,
    int* __restrict__ bucketCur, uint2* __restrict__ spair, int N, int nG, int nCB){
  __shared__ int hist[256];
  __shared__ int sbase[256];
  int bid = blockIdx.x;
  int m = bid % 3;
  if (m < 2){
    int g = (bid/3)*2 + m;
    if (g < nG)
      gemm_mfma<0>(posts, (const _Float16*)Wf1, nullptr, nullptr, xw1u, N, 0, g);
  } else {
    int cb = bid / 3;
    if (cb >= nCB) return;
    int t = threadIdx.x;
    hist[t] = 0;
    __syncthreads();
    int base_e = cb*2048 + t;
    int bq[8], lr[8], rq[8], cq[8];
    #pragma unroll
    for (int q = 0; q < 8; q++){
      int e = base_e + q*256;
      if (e < E){
        cq[q] = col[e];
        rq[q] = row[e];
        bq[q] = cq[q] >> BSHIFT;
        lr[q] = atomicAdd(&hist[bq[q]], 1);     // LDS atomic
      } else bq[q] = -1;
    }
    __syncthreads();
    int h = hist[t];
    if (h > 0) sbase[t] = atomicAdd(&bucketCur[t], h);  // 1 global atomic/bucket
    __syncthreads();
    #pragma unroll
    for (int q = 0; q < 8; q++){
      if (bq[q] >= 0){
        int p = sbase[bq[q]] + lr[q];
        if (p < MAXBE)
          spair[(size_t)bq[q]*MAXBE + p] = make_uint2((unsigned)rq[q], (unsigned)cq[q]);
      }
    }
  }
}

// ---- build: one block per bucket; LDS-atomic per-node ranks ----
__global__ __launch_bounds__(256) void k_build(const uint2* __restrict__ spair,
    const int* __restrict__ bucketCur, int* __restrict__ csrp,
    int* __restrict__ cnt, int N){
  __shared__ int c512[512];
  int b = blockIdx.x;
  int t = threadIdx.x;
  c512[t] = 0; c512[t + 256] = 0;
  __syncthreads();
  int nb = bucketCur[b]; if (nb > MAXBE) nb = MAXBE;
  const uint2* sp = spair + (size_t)b*MAXBE;
  for (int i = t; i < nb; i += 256){
    uint2 pr = sp[i];
    int c = (int)pr.y;
    int rank = atomicAdd(&c512[c & 511], 1);    // LDS atomic
    if (rank < CSTRIDE)
      csrp[(size_t)c*CSTRIDE + rank] = (int)pr.x;
  }
  __syncthreads();
  int n0 = (b << BSHIFT) + t;
  if (n0 < N) cnt[n0] = c512[t];
  int n1 = n0 + 256;
  if (n1 < ((b + 1) << BSHIFT) && n1 < N) cnt[n1] = c512[t + 256];
}

// ---- root: c1root (f32, 4-deep pipelined gather of root's row), cvec, cpool ----
__global__ void k_root(const __half* __restrict__ xw1u, const int* __restrict__ csrp,
                       const int* __restrict__ cnt, const float* __restrict__ b1,
                       const float* __restrict__ posts, const float* __restrict__ W2,
                       const int* __restrict__ rootIdx,
                       float* __restrict__ cvec, float* __restrict__ cpool){
  __shared__ float cr[DIM];
  __shared__ float pr[DIM];
  int t = threadIdx.x;                          // 128 threads
  int root = rootIdx[0];
  int rc = cnt[root];
  float dvr = rsqrtf((float)(rc + 1));
  const int* lst = csrp + (size_t)root*CSTRIDE;
  float a = __half2float(xw1u[(size_t)root*DIM + t]) * dvr;
  int i = 0;
  for (; i + 4 <= rc; i += 4){
    int r0 = lst[i], r1 = lst[i+1], r2 = lst[i+2], r3 = lst[i+3];
    float f0 = __half2float(xw1u[(size_t)r0*DIM + t]) * rsqrtf((float)(cnt[r0] + 1));
    float f1 = __half2float(xw1u[(size_t)r1*DIM + t]) * rsqrtf((float)(cnt[r1] + 1));
    float f2 = __half2float(xw1u[(size_t)r2*DIM + t]) * rsqrtf((float)(cnt[r2] + 1));
    float f3 = __half2float(xw1u[(size_t)r3*DIM + t]) * rsqrtf((float)(cnt[r3] + 1));
    a += (f0 + f1) + (f2 + f3);
  }
  for (; i < rc; i++){
    int r = lst[i];
    a += __half2float(xw1u[(size_t)r*DIM + t]) * rsqrtf((float)(cnt[r] + 1));
  }
  cr[t] = dvr*a + b1[t];
  pr[t] = fmaxf(posts[(size_t)root*DIM + t], 0.f);
  __syncthreads();
  float s = 0.f;
  #pragma unroll 4
  for (int k = 0; k < DIM; k++) s += pr[k] * W2[(size_t)(DIM + k)*DIM + t];
  cvec[t] = s;
  cpool[t] = (t < 126) ? (cr[t] + cr[t+1] + cr[t+2]) * (1.f/3.f) : cr[t];
}

// ---- conv1 per-node work (one wave, 2 halves cooperating, depth-8 pipeline) ----
__device__ __forceinline__ void conv1_work(int v, const __half* __restrict__ xw1u,
    const int* __restrict__ csrp, const int* __restrict__ cnt,
    const float* __restrict__ b, __half* __restrict__ outh){
  int lane = threadIdx.x & 63;
  int half = lane >> 5;
  int sl   = lane & 31;
  float dv = rsqrtf((float)(cnt[v] + 1));
  long long o0 = (long long)v * CSTRIDE;
  int total = cnt[v] + 1;                       // virtual entry 0 = self

  __half2 a01 = __float2half2_rn(0.f), a23 = __float2half2_rn(0.f);
  const __half* base = xw1u;

  auto idx = [&](int t){ return (t == 0) ? v : csrp[o0 + t - 1]; };
  auto dhv = [&](int r){ return __float2half_rn(rsqrtf((float)(cnt[r] + 1))); };
  auto accum = [&](uint2 wv, __half dh){
    __half2 d2 = __half2half2(dh);
    a01 = __hfma2(*(__half2*)&wv.x, d2, a01);
    a23 = __hfma2(*(__half2*)&wv.y, d2, a23);
  };

  int j = half;
  if (j + 14 < total){
    int nid[8];
    #pragma unroll
    for (int q = 0; q < 8; q++) nid[q] = idx(j + 2*q);
    while (j + 14 < total){
      int cur[8];
      #pragma unroll
      for (int q = 0; q < 8; q++) cur[q] = nid[q];
      int jn = j + 16;
      if (jn + 14 < total){
        #pragma unroll
        for (int q = 0; q < 8; q++) nid[q] = csrp[o0 + jn + 2*q - 1];
      }
      uint2 u[8]; __half dh[8];
      #pragma unroll
      for (int q = 0; q < 8; q++){
        u[q]  = *(const uint2*)(base + (size_t)cur[q]*DIM + sl*4);
        dh[q] = dhv(cur[q]);
      }
      #pragma unroll
      for (int q = 0; q < 8; q++) accum(u[q], dh[q]);
      j = jn;
    }
  }
  while (j + 6 < total){
    int i0 = idx(j), i1 = idx(j+2), i2 = idx(j+4), i3 = idx(j+6);
    uint2 u0 = *(const uint2*)(base + (size_t)i0*DIM + sl*4);
    uint2 u1 = *(const uint2*)(base + (size_t)i1*DIM + sl*4);
    uint2 u2 = *(const uint2*)(base + (size_t)i2*DIM + sl*4);
    uint2 u3 = *(const uint2*)(base + (size_t)i3*DIM + sl*4);
    __half d0 = dhv(i0), d1 = dhv(i1), d2 = dhv(i2), d3 = dhv(i3);
    accum(u0, d0); accum(u1, d1); accum(u2, d2); accum(u3, d3);
    j += 8;
  }
  for (; j < total; j += 2){
    int r = idx(j);
    uint2 u = *(const uint2*)(base + (size_t)r*DIM + sl*4);
    accum(u, dhv(r));
  }

  int r01 = __shfl_xor(*(int*)&a01, 32);
  int r23 = __shfl_xor(*(int*)&a23, 32);
  a01 = __hadd2(a01, *(__half2*)&r01);
  a23 = __hadd2(a23, *(__half2*)&r23);

  if (half == 0){
    float2 f01 = __half22float2(a01), f23 = __half22float2(a23);
    float4 bb = *(const float4*)(b + sl*4);
    float rx = dv*f01.x + bb.x, ry = dv*f01.y + bb.y;
    float rz = dv*f23.x + bb.z, rw = dv*f23.y + bb.w;
    __half2 h01 = __floats2half2_rn(rx, ry);
    __half2 h23 = __floats2half2_rn(rz, rw);
    uint2 u = make_uint2(*(unsigned int*)&h01, *(unsigned int*)&h23);
    *(uint2*)(outh + (size_t)v*DIM + sl*4) = u;
  }
}

// ---- conv1a: blocks [0,nCv1) = conv1 nodes [0,Nh); blocks [nCv1,nCv1+nF) = fill ----
__global__ __launch_bounds__(256) void k_conv1a(const __half* __restrict__ xw1u,
    const int* __restrict__ csrp, const int* __restrict__ cnt,
    const float* __restrict__ b, __half* __restrict__ c1h,
    const float* __restrict__ cpool, float* __restrict__ outp,
    int N, int Nh, int nCv1, int nF){
  int bid = blockIdx.x;
  if (bid < nCv1){
    int v = bid*4 + (threadIdx.x >> 6);
    if (v < Nh) conv1_work(v, xw1u, csrp, cnt, b, c1h);
  } else {
    int f = bid - nCv1;
    if (f >= nF) return;
    int total = N * 63;                         // float2 slots for cols 0..125
    #pragma unroll
    for (int i = 0; i < 8; i++){
      int w = f*2048 + i*256 + threadIdx.x;
      if (w < total){
        unsigned int r  = (unsigned int)w / 63u;
        unsigned int c2 = (unsigned int)w - r*63u;
        float2 val = *(const float2*)(cpool + c2*2);
        *(float2*)(outp + (size_t)r*254 + c2*2) = val;
      }
    }
  }
}

// ---- megaD: per 17 blocks, 16 = conv1 nodes [Nh,N), 1 = gemm2 rows [0,Nh) ----
__global__ __launch_bounds__(256) void k_megaD(const __half* __restrict__ xw1u,
    const int* __restrict__ csrp, const int* __restrict__ cnt,
    const float* __restrict__ b, __half* __restrict__ c1h,
    const __half* __restrict__ Wf2, const float* __restrict__ cvec,
    __half* __restrict__ xw2s, int N, int Nh, int nCv2, int nGa){
  int bid = blockIdx.x;
  int m = bid % 17;
  if (m < 16){
    int cb = (bid/17)*16 + m;
    if (cb < nCv2){
      int v = Nh + cb*4 + (threadIdx.x >> 6);
      if (v < N) conv1_work(v, xw1u, csrp, cnt, b, c1h);
    }
  } else {
    int g = bid / 17;
    if (g < nGa)
      gemm_mfma<1>(c1h, (const _Float16*)Wf2, cvec, cnt, xw2s, N, 1, g);
  }
}

// ---- megaC2: gemm2 rows [Nh,N) only ----
__global__ __launch_bounds__(256) void k_megaC2(const __half* __restrict__ c1h,
    const __half* __restrict__ Wf2, const float* __restrict__ cvec,
    const int* __restrict__ cnt, __half* __restrict__ xw2s, int N, int gb0){
  gemm_mfma<1>(c1h, (const _Float16*)Wf2, cvec, cnt, xw2s, N, 1, gb0 + blockIdx.x);
}

// ---- conv2: prescaled gather, pk-f16 accumulate, relu + fused pooling ----
__global__ void k_conv2(const __half* __restrict__ xws, const int* __restrict__ csrp,
                        const int* __restrict__ cnt,
                        const float* __restrict__ b2,
                        const float* __restrict__ cpool, float* __restrict__ out, int N){
  int wid  = (blockIdx.x*blockDim.x + threadIdx.x) >> 6;
  if (wid >= N) return;
  int lane = threadIdx.x & 63;
  int half = lane >> 5;
  int sl   = lane & 31;
  int v = wid;
  float dv = rsqrtf((float)(cnt[v] + 1));
  long long o0 = (long long)v * CSTRIDE;
  int total = cnt[v] + 1;

  __half2 a01 = __float2half2_rn(0.f), a23 = __float2half2_rn(0.f);
  const __half* base = xws;

  auto idx = [&](int t){ return (t == 0) ? v : csrp[o0 + t - 1]; };
  auto accum = [&](uint2 wv){
    a01 = __hadd2(a01, *(__half2*)&wv.x);
    a23 = __hadd2(a23, *(__half2*)&wv.y);
  };

  int j = half;
  if (j + 14 < total){
    int nid[8];
    #pragma unroll
    for (int q = 0; q < 8; q++) nid[q] = idx(j + 2*q);
    while (j + 14 < total){
      int cur[8];
      #pragma unroll
      for (int q = 0; q < 8; q++) cur[q] = nid[q];
      int jn = j + 16;
      if (jn + 14 < total){
        #pragma unroll
        for (int q = 0; q < 8; q++) nid[q] = csrp[o0 + jn + 2*q - 1];
      }
      uint2 u[8];
      #pragma unroll
      for (int q = 0; q < 8; q++) u[q] = *(const uint2*)(base + (size_t)cur[q]*DIM + sl*4);
      #pragma unroll
      for (int q = 0; q < 8; q++) accum(u[q]);
      j = jn;
    }
  }
  while (j + 6 < total){
    int i0 = idx(j), i1 = idx(j+2), i2 = idx(j+4), i3 = idx(j+6);
    uint2 u0 = *(const uint2*)(base + (size_t)i0*DIM + sl*4);
    uint2 u1 = *(const uint2*)(base + (size_t)i1*DIM + sl*4);
    uint2 u2 = *(const uint2*)(base + (size_t)i2*DIM + sl*4);
    uint2 u3 = *(const uint2*)(base + (size_t)i3*DIM + sl*4);
    accum(u0); accum(u1); accum(u2); accum(u3);
    j += 8;
  }
  for (; j < total; j += 2){
    uint2 u = *(const uint2*)(base + (size_t)idx(j)*DIM + sl*4);
    accum(u);
  }

  int r01 = __shfl_xor(*(int*)&a01, 32);
  int r23 = __shfl_xor(*(int*)&a23, 32);
  a01 = __hadd2(a01, *(__half2*)&r01);
  a23 = __hadd2(a23, *(__half2*)&r23);

  if (half == 0){
    float2 f01 = __half22float2(a01), f23 = __half22float2(a23);
    float4 bb = *(const float4*)(b2 + sl*4);
    float o0v = fmaxf(dv*f01.x + bb.x, 0.f);    // co[4sl+0]
    float o1v = fmaxf(dv*f01.y + bb.y, 0.f);    // co[4sl+1]
    float o2v = fmaxf(dv*f23.x + bb.z, 0.f);    // co[4sl+2]
    float o3v = fmaxf(dv*f23.y + bb.w, 0.f);    // co[4sl+3]

    // pooled col 126+t needs co[t-2..t]; prev lane supplies co[4sl-2], co[4sl-1]
    float pz = __shfl_up(o2v, 1);
    float pw = __shfl_up(o3v, 1);
    if (sl == 0){ pz = cpool[126]; pw = cpool[127]; }
    const float third = 1.f/3.f;
    float q0 = (pz + pw + o0v) * third;
    float q1 = (pw + o0v + o1v) * third;
    float q2 = (o0v + o1v + o2v) * third;
    float q3 = (o1v + o2v + o3v) * third;

    float* orow = out + (size_t)v*254;
    *(float2*)(orow + 126 + sl*4)     = make_float2(q0, q1);
    *(float2*)(orow + 126 + sl*4 + 2) = make_float2(q2, q3);
  }
}

extern "C" void kernel_launch(void* const* d_in, const int* in_sizes, int n_in,
                              void* d_out, int out_size, void* d_ws, size_t ws_size,
                              hipStream_t stream){
  const float* posts = (const float*)d_in[0];
  const float* W1    = (const float*)d_in[1];
  const float* b1    = (const float*)d_in[2];
  const float* W2    = (const float*)d_in[3];
  const float* b2    = (const float*)d_in[4];
  const int*   eidx  = (const int*)d_in[5];
  const int*   rootI = (const int*)d_in[6];
  int N = in_sizes[0] / DIM;
  int E = in_sizes[5] / 2;
  const int* row = eidx;
  const int* col = eidx + E;

  char* p = (char*)d_ws;
  auto alloc = [&](size_t bytes)->void*{
    void* q = (void*)p; p += (bytes + 255) & ~(size_t)255; return q;
  };
  __half* xw1u  = (__half*)alloc((size_t)N*DIM*2);
  __half* xw2s  = (__half*)alloc((size_t)N*DIM*2);
  __half* c1h   = (__half*)alloc((size_t)N*DIM*2);
  __half* Wf1   = (__half*)alloc((size_t)DIM*DIM*2);
  __half* Wf2   = (__half*)alloc((size_t)DIM*DIM*2);
  float* cvec   = (float*)alloc(DIM*4);
  float* cpool  = (float*)alloc(DIM*4);
  int*   cnt    = (int*)alloc((size_t)N*4);
  int*   csrp   = (int*)alloc((size_t)N*CSTRIDE*4);
  int*   bCur   = (int*)alloc(256*4);
  int    NBUCK  = (N + (1 << BSHIFT) - 1) >> BSHIFT;   // 196
  uint2* spair  = (uint2*)alloc((size_t)NBUCK*MAXBE*8);

  int nG  = (N + 63) / 64;                      // 1563 gemm1 blocks
  int nCB = (E + 2047) / 2048;                  // 782 bucket blocks
  int q3  = ((nG + 1)/2 > nCB) ? (nG + 1)/2 : nCB;
  int nF  = (N*63 + 2047) / 2048;

  int Nh   = ((N/2 + 63)/64)*64;                // 50048, 64- and 4-aligned
  if (Nh > N) Nh = (N/64)*64;
  int nCv1 = (Nh + 3)/4;                        // 12512
  int nCv2 = (N - Nh + 3)/4;                    // 12488
  int nGa  = Nh/64;                             // 782 (gemm2 first part)
  int nGb  = (N - Nh + 63)/64;                  // 781 (gemm2 second part)
  int q17  = ((nCv2 + 15)/16 > nGa) ? (nCv2 + 15)/16 : nGa;

  k_wprep<<<16, 256, 0, stream>>>(W1, W2, Wf1, Wf2, bCur);
  k_megaB<<<3*q3, 256, 0, stream>>>(posts, Wf1, xw1u, row, col, E, bCur, spair, N, nG, nCB);
  k_build<<<NBUCK, 256, 0, stream>>>(spair, bCur, csrp, cnt, N);
  k_root <<<1, 128, 0, stream>>>(xw1u, csrp, cnt, b1, posts, W2, rootI, cvec, cpool);
  k_conv1a<<<nCv1 + nF, 256, 0, stream>>>(xw1u, csrp, cnt, b1, c1h, cpool,
                                          (float*)d_out, N, Nh, nCv1, nF);
  k_megaD<<<17*q17, 256, 0, stream>>>(xw1u, csrp, cnt, b1, c1h, Wf2, cvec,
                                      xw2s, N, Nh, nCv2, nGa);
  k_megaC2<<<nGb, 256, 0, stream>>>(c1h, Wf2, cvec, cnt, xw2s, N, nGa);
  k_conv2<<<(N + 3)/4, 256, 0, stream>>>(xw2s, csrp, cnt, b2, cpool,
                                         (float*)d_out, N);
}

// Round 22
// 239.020 us; speedup vs baseline: 1.1405x; 1.1405x over previous
//
#include <hip/hip_runtime.h>
#include <hip/hip_fp16.h>

#define DIM 128
#define CSTRIDE 64
#define BSHIFT 9
#define MAXBE 9216
typedef _Float16 half8 __attribute__((ext_vector_type(8)));
typedef float f32x4 __attribute__((ext_vector_type(4)));

// ---- pack W1,W2[0:128] into MFMA B-fragments; 16 blocks (8 per matrix) ----
// Also zeroes bucketCur (256 ints).
// Wf[(ct*4+kc)*64 + lane][i] = (f16) W[kc*32 + (lane>>4)*8 + i][ct*16 + (lane&15)]
__global__ void k_wprep(const float* __restrict__ W1, const float* __restrict__ W2,
                        __half* __restrict__ Wf1h, __half* __restrict__ Wf2h,
                        int* __restrict__ bucketCur){
  const float* Wsrc = (blockIdx.x < 8) ? W1 : W2;
  _Float16* Wf = (_Float16*)((blockIdx.x < 8) ? Wf1h : Wf2h);
  int id   = (blockIdx.x & 7)*256 + threadIdx.x; // (ct*4+kc)*64 + lane
  int lane = id & 63;
  int ckc  = id >> 6;
  int kc   = ckc & 3, ct = ckc >> 2;
  int kbase = kc*32 + (lane >> 4)*8;
  int c     = ct*16 + (lane & 15);
  half8 v;
  #pragma unroll
  for (int i = 0; i < 8; i++)
    v[i] = (_Float16)Wsrc[(size_t)(kbase + i)*DIM + c];
  *(half8*)(Wf + (size_t)id*8) = v;
  if (blockIdx.x == 0) bucketCur[threadIdx.x] = 0;
}

// ---- MFMA GEMM tile (device fn): Yh[64 rows](f16) = scale * ((relu?)X @ W + addvec)
// scale = rsqrt(cnt[r]+1) if cntp else 1.
template<int INH>
__device__ __forceinline__ void gemm_mfma(const void* __restrict__ Xv,
    const _Float16* __restrict__ Wf, const float* __restrict__ addvec,
    const int* __restrict__ cntp, __half* __restrict__ Yh, int N, int doRelu, int gb){
  int wid = threadIdx.x >> 6;
  int l   = threadIdx.x & 63;
  int g   = l >> 4;
  int lr  = l & 15;
  int rowA = gb*64 + wid*16 + lr;
  int rA   = (rowA < N) ? rowA : (N - 1);

  f32x4 acc[8];
  #pragma unroll
  for (int ct = 0; ct < 8; ct++) acc[ct] = (f32x4){0.f, 0.f, 0.f, 0.f};

  #pragma unroll
  for (int kc = 0; kc < 4; kc++){
    half8 a;
    if (INH){
      a = *(const half8*)((const _Float16*)Xv + (size_t)rA*DIM + kc*32 + g*8);
    } else {
      const float* xp = (const float*)Xv + (size_t)rA*DIM + kc*32 + g*8;
      float4 x0 = *(const float4*)xp;
      float4 x1 = *(const float4*)(xp + 4);
      a[0]=(_Float16)x0.x; a[1]=(_Float16)x0.y; a[2]=(_Float16)x0.z; a[3]=(_Float16)x0.w;
      a[4]=(_Float16)x1.x; a[5]=(_Float16)x1.y; a[6]=(_Float16)x1.z; a[7]=(_Float16)x1.w;
    }
    if (doRelu){
      #pragma unroll
      for (int i = 0; i < 8; i++) a[i] = (a[i] > (_Float16)0.f) ? a[i] : (_Float16)0.f;
    }
    #pragma unroll
    for (int ct = 0; ct < 8; ct++){
      half8 b = *(const half8*)(Wf + ((size_t)(ct*4 + kc)*64 + l)*8);
      acc[ct] = __builtin_amdgcn_mfma_f32_16x16x32_f16(a, b, acc[ct], 0, 0, 0);
    }
  }

  // C/D layout (HW-verified): col = lane&15, row = (lane>>4)*4 + reg
  int m0 = gb*64 + wid*16 + g*4;
  float av[8];
  #pragma unroll
  for (int ct = 0; ct < 8; ct++) av[ct] = addvec ? addvec[ct*16 + lr] : 0.f;
  #pragma unroll
  for (int r = 0; r < 4; r++){
    int rr = m0 + r;
    if (rr < N){
      float dv = cntp ? rsqrtf((float)(cntp[rr] + 1)) : 1.f;
      #pragma unroll
      for (int ct = 0; ct < 8; ct++){
        float o = dv*(acc[ct][r] + av[ct]);
        Yh[(size_t)rr*DIM + ct*16 + lr] = __float2half(o);
      }
    }
  }
}

// ---- megaB: per 3 blocks, 2 = gemm1 (unscaled), 1 = LDS-aggregated bucket scatter.
// Bucket = col>>9 (512 nodes). Per block: LDS histogram over <=256 buckets,
// ONE global atomic per (block,bucket) reserves a contiguous range in the
// bucket's fixed region, then (row,col) pairs written near-contiguously.
// Global atomics: ~196*nCB ~ 153K (10x fewer than per-edge).
__global__ __launch_bounds__(256) void k_megaB(const float* __restrict__ posts,
    const __half* __restrict__ Wf1, __half* __restrict__ xw1u,
    const int* __restrict__ row, const int* __restrict__ col, int E,
    int* __restrict__ bucketCur, uint2* __restrict__ spair, int N, int nG, int nCB){
  __shared__ int hist[256];
  __shared__ int sbase[256];
  int bid = blockIdx.x;
  int m = bid % 3;
  if (m < 2){
    int g = (bid/3)*2 + m;
    if (g < nG)
      gemm_mfma<0>(posts, (const _Float16*)Wf1, nullptr, nullptr, xw1u, N, 0, g);
  } else {
    int cb = bid / 3;
    if (cb >= nCB) return;
    int t = threadIdx.x;
    hist[t] = 0;
    __syncthreads();
    int base_e = cb*2048 + t;
    int bq[8], lr[8], rq[8], cq[8];
    #pragma unroll
    for (int q = 0; q < 8; q++){
      int e = base_e + q*256;
      if (e < E){
        cq[q] = col[e];
        rq[q] = row[e];
        bq[q] = cq[q] >> BSHIFT;
        lr[q] = atomicAdd(&hist[bq[q]], 1);     // LDS atomic
      } else bq[q] = -1;
    }
    __syncthreads();
    int h = hist[t];
    if (h > 0) sbase[t] = atomicAdd(&bucketCur[t], h);  // 1 global atomic/bucket
    __syncthreads();
    #pragma unroll
    for (int q = 0; q < 8; q++){
      if (bq[q] >= 0){
        int p = sbase[bq[q]] + lr[q];
        if (p < MAXBE)                          // 11-sigma guard
          spair[(size_t)bq[q]*MAXBE + p] = make_uint2((unsigned)rq[q], (unsigned)cq[q]);
      }
    }
  }
}

// ---- build: one block per bucket; LDS-atomic per-node ranks (globally unique
// since all edges of node c land in bucket c>>9); writes csrp + cnt.
__global__ __launch_bounds__(256) void k_build(const uint2* __restrict__ spair,
    const int* __restrict__ bucketCur, int* __restrict__ csrp,
    int* __restrict__ cnt, int N){
  __shared__ int c512[512];
  int b = blockIdx.x;
  int t = threadIdx.x;
  c512[t] = 0; c512[t + 256] = 0;
  __syncthreads();
  int nb = bucketCur[b]; if (nb > MAXBE) nb = MAXBE;
  const uint2* sp = spair + (size_t)b*MAXBE;
  for (int i = t; i < nb; i += 256){
    uint2 pr = sp[i];
    int c = (int)pr.y;
    int rank = atomicAdd(&c512[c & 511], 1);    // LDS atomic
    if (rank < CSTRIDE)
      csrp[(size_t)c*CSTRIDE + rank] = (int)pr.x;
  }
  __syncthreads();
  int n0 = (b << BSHIFT) + t;
  if (n0 < N) cnt[n0] = c512[t];
  int n1 = n0 + 256;
  if (n1 < ((b + 1) << BSHIFT) && n1 < N) cnt[n1] = c512[t + 256];
}

// ---- megaC: blocks [0,nG) = gemm2 (cnt-prescaled, relu-on-load);
//      blocks [nG,nG+nF) = const-column fill of d_out cols 0..125 ----
__global__ __launch_bounds__(256) void k_megaC(const __half* __restrict__ c1h,
    const __half* __restrict__ Wf2, const float* __restrict__ cvec,
    const int* __restrict__ cnt, __half* __restrict__ xw2s,
    const float* __restrict__ cpool, float* __restrict__ outp, int N, int nG, int nF){
  int bid = blockIdx.x;
  if (bid < nG){
    gemm_mfma<1>(c1h, (const _Float16*)Wf2, cvec, cnt, xw2s, N, 1, bid);
  } else {
    int f = bid - nG;
    if (f >= nF) return;
    int total = N * 63;                         // float2 slots for cols 0..125
    #pragma unroll
    for (int i = 0; i < 8; i++){
      int w = f*2048 + i*256 + threadIdx.x;
      if (w < total){
        unsigned int r  = (unsigned int)w / 63u;
        unsigned int c2 = (unsigned int)w - r*63u;
        float2 val = *(const float2*)(cpool + c2*2);
        *(float2*)(outp + (size_t)r*254 + c2*2) = val;
      }
    }
  }
}

// ---- conv1: one wave/node, 2 rows/wave, 8-deep pipeline, pk-f16 accumulate ----
__global__ void k_conv1(const __half* __restrict__ xw1u, const int* __restrict__ csrp,
                        const int* __restrict__ cnt,
                        const float* __restrict__ b, const int* __restrict__ rootIdx,
                        __half* __restrict__ outh, float* __restrict__ c1root, int N){
  int wid  = (blockIdx.x*blockDim.x + threadIdx.x) >> 6;
  if (wid >= N) return;
  int lane = threadIdx.x & 63;
  int half = lane >> 5;
  int sl   = lane & 31;
  int v = wid;
  float dv = rsqrtf((float)(cnt[v] + 1));
  long long o0 = (long long)v * CSTRIDE;
  int total = cnt[v] + 1;                       // virtual entry 0 = self

  __half2 a01 = __float2half2_rn(0.f), a23 = __float2half2_rn(0.f);
  const __half* base = xw1u;

  auto idx = [&](int t){ return (t == 0) ? v : csrp[o0 + t - 1]; };
  auto dhv = [&](int r){ return __float2half_rn(rsqrtf((float)(cnt[r] + 1))); };
  auto accum = [&](uint2 wv, __half dh){
    __half2 d2 = __half2half2(dh);
    a01 = __hfma2(*(__half2*)&wv.x, d2, a01);
    a23 = __hfma2(*(__half2*)&wv.y, d2, a23);
  };

  int j = half;
  if (j + 14 < total){
    int nid[8];
    #pragma unroll
    for (int q = 0; q < 8; q++) nid[q] = idx(j + 2*q);
    while (j + 14 < total){
      int cur[8];
      #pragma unroll
      for (int q = 0; q < 8; q++) cur[q] = nid[q];
      int jn = j + 16;
      if (jn + 14 < total){
        #pragma unroll
        for (int q = 0; q < 8; q++) nid[q] = csrp[o0 + jn + 2*q - 1];
      }
      uint2 u[8]; __half dh[8];
      #pragma unroll
      for (int q = 0; q < 8; q++){
        u[q]  = *(const uint2*)(base + (size_t)cur[q]*DIM + sl*4);
        dh[q] = dhv(cur[q]);
      }
      #pragma unroll
      for (int q = 0; q < 8; q++) accum(u[q], dh[q]);
      j = jn;
    }
  }
  while (j + 6 < total){
    int i0 = idx(j), i1 = idx(j+2), i2 = idx(j+4), i3 = idx(j+6);
    uint2 u0 = *(const uint2*)(base + (size_t)i0*DIM + sl*4);
    uint2 u1 = *(const uint2*)(base + (size_t)i1*DIM + sl*4);
    uint2 u2 = *(const uint2*)(base + (size_t)i2*DIM + sl*4);
    uint2 u3 = *(const uint2*)(base + (size_t)i3*DIM + sl*4);
    __half d0 = dhv(i0), d1 = dhv(i1), d2 = dhv(i2), d3 = dhv(i3);
    accum(u0, d0); accum(u1, d1); accum(u2, d2); accum(u3, d3);
    j += 8;
  }
  for (; j < total; j += 2){
    int r = idx(j);
    uint2 u = *(const uint2*)(base + (size_t)r*DIM + sl*4);
    accum(u, dhv(r));
  }

  int r01 = __shfl_xor(*(int*)&a01, 32);
  int r23 = __shfl_xor(*(int*)&a23, 32);
  a01 = __hadd2(a01, *(__half2*)&r01);
  a23 = __hadd2(a23, *(__half2*)&r23);

  if (half == 0){
    float2 f01 = __half22float2(a01), f23 = __half22float2(a23);
    float4 bb = *(const float4*)(b + sl*4);
    float rx = dv*f01.x + bb.x, ry = dv*f01.y + bb.y;
    float rz = dv*f23.x + bb.z, rw = dv*f23.y + bb.w;
    __half2 h01 = __floats2half2_rn(rx, ry);
    __half2 h23 = __floats2half2_rn(rz, rw);
    uint2 u = make_uint2(*(unsigned int*)&h01, *(unsigned int*)&h23);
    *(uint2*)(outh + (size_t)v*DIM + sl*4) = u;
    if (v == rootIdx[0])
      *(float4*)(c1root + sl*4) = make_float4(rx, ry, rz, rw);
  }
}

// cvec[j] = relu(posts[root]) @ W2[128:256]; cpool = pooled const cols + raw cr[126..127]
__global__ void k_small(const float* __restrict__ posts, const float* __restrict__ W2,
                        const float* __restrict__ c1root, const int* __restrict__ rootIdx,
                        float* __restrict__ cvec, float* __restrict__ cpool){
  int j = threadIdx.x;                          // 128 threads
  int root = rootIdx[0];
  __shared__ float pr[DIM];
  __shared__ float cr[DIM];
  pr[j] = fmaxf(posts[(size_t)root*DIM + j], 0.f);
  cr[j] = c1root[j];
  __syncthreads();
  float s = 0.f;
  #pragma unroll 4
  for (int k = 0; k < DIM; k++) s += pr[k] * W2[(size_t)(DIM + k)*DIM + j];
  cvec[j] = s;
  cpool[j] = (j < 126) ? (cr[j] + cr[j+1] + cr[j+2]) * (1.f/3.f) : cr[j];
}

// ---- conv2: prescaled gather, pk-f16 accumulate, relu + fused pooling ----
// writes ONLY pooled cols 126..253 (const cols filled by megaC)
__global__ void k_conv2(const __half* __restrict__ xws, const int* __restrict__ csrp,
                        const int* __restrict__ cnt,
                        const float* __restrict__ b2,
                        const float* __restrict__ cpool, float* __restrict__ out, int N){
  int wid  = (blockIdx.x*blockDim.x + threadIdx.x) >> 6;
  if (wid >= N) return;
  int lane = threadIdx.x & 63;
  int half = lane >> 5;
  int sl   = lane & 31;
  int v = wid;
  float dv = rsqrtf((float)(cnt[v] + 1));
  long long o0 = (long long)v * CSTRIDE;
  int total = cnt[v] + 1;

  __half2 a01 = __float2half2_rn(0.f), a23 = __float2half2_rn(0.f);
  const __half* base = xws;

  auto idx = [&](int t){ return (t == 0) ? v : csrp[o0 + t - 1]; };
  auto accum = [&](uint2 wv){
    a01 = __hadd2(a01, *(__half2*)&wv.x);
    a23 = __hadd2(a23, *(__half2*)&wv.y);
  };

  int j = half;
  if (j + 14 < total){
    int nid[8];
    #pragma unroll
    for (int q = 0; q < 8; q++) nid[q] = idx(j + 2*q);
    while (j + 14 < total){
      int cur[8];
      #pragma unroll
      for (int q = 0; q < 8; q++) cur[q] = nid[q];
      int jn = j + 16;
      if (jn + 14 < total){
        #pragma unroll
        for (int q = 0; q < 8; q++) nid[q] = csrp[o0 + jn + 2*q - 1];
      }
      uint2 u[8];
      #pragma unroll
      for (int q = 0; q < 8; q++) u[q] = *(const uint2*)(base + (size_t)cur[q]*DIM + sl*4);
      #pragma unroll
      for (int q = 0; q < 8; q++) accum(u[q]);
      j = jn;
    }
  }
  while (j + 6 < total){
    int i0 = idx(j), i1 = idx(j+2), i2 = idx(j+4), i3 = idx(j+6);
    uint2 u0 = *(const uint2*)(base + (size_t)i0*DIM + sl*4);
    uint2 u1 = *(const uint2*)(base + (size_t)i1*DIM + sl*4);
    uint2 u2 = *(const uint2*)(base + (size_t)i2*DIM + sl*4);
    uint2 u3 = *(const uint2*)(base + (size_t)i3*DIM + sl*4);
    accum(u0); accum(u1); accum(u2); accum(u3);
    j += 8;
  }
  for (; j < total; j += 2){
    uint2 u = *(const uint2*)(base + (size_t)idx(j)*DIM + sl*4);
    accum(u);
  }

  int r01 = __shfl_xor(*(int*)&a01, 32);
  int r23 = __shfl_xor(*(int*)&a23, 32);
  a01 = __hadd2(a01, *(__half2*)&r01);
  a23 = __hadd2(a23, *(__half2*)&r23);

  if (half == 0){
    float2 f01 = __half22float2(a01), f23 = __half22float2(a23);
    float4 bb = *(const float4*)(b2 + sl*4);
    float o0v = fmaxf(dv*f01.x + bb.x, 0.f);    // co[4sl+0]
    float o1v = fmaxf(dv*f01.y + bb.y, 0.f);    // co[4sl+1]
    float o2v = fmaxf(dv*f23.x + bb.z, 0.f);    // co[4sl+2]
    float o3v = fmaxf(dv*f23.y + bb.w, 0.f);    // co[4sl+3]

    // pooled col 126+t needs co[t-2..t]; prev lane supplies co[4sl-2], co[4sl-1]
    float pz = __shfl_up(o2v, 1);
    float pw = __shfl_up(o3v, 1);
    if (sl == 0){ pz = cpool[126]; pw = cpool[127]; }
    const float third = 1.f/3.f;
    float q0 = (pz + pw + o0v) * third;
    float q1 = (pw + o0v + o1v) * third;
    float q2 = (o0v + o1v + o2v) * third;
    float q3 = (o1v + o2v + o3v) * third;

    float* orow = out + (size_t)v*254;
    *(float2*)(orow + 126 + sl*4)     = make_float2(q0, q1);
    *(float2*)(orow + 126 + sl*4 + 2) = make_float2(q2, q3);
  }
}

extern "C" void kernel_launch(void* const* d_in, const int* in_sizes, int n_in,
                              void* d_out, int out_size, void* d_ws, size_t ws_size,
                              hipStream_t stream){
  const float* posts = (const float*)d_in[0];
  const float* W1    = (const float*)d_in[1];
  const float* b1    = (const float*)d_in[2];
  const float* W2    = (const float*)d_in[3];
  const float* b2    = (const float*)d_in[4];
  const int*   eidx  = (const int*)d_in[5];
  const int*   rootI = (const int*)d_in[6];
  int N = in_sizes[0] / DIM;
  int E = in_sizes[5] / 2;
  const int* row = eidx;
  const int* col = eidx + E;

  char* p = (char*)d_ws;
  auto alloc = [&](size_t bytes)->void*{
    void* q = (void*)p; p += (bytes + 255) & ~(size_t)255; return q;
  };
  __half* xw1u  = (__half*)alloc((size_t)N*DIM*2);
  __half* xw2s  = (__half*)alloc((size_t)N*DIM*2);
  __half* c1h   = (__half*)alloc((size_t)N*DIM*2);
  __half* Wf1   = (__half*)alloc((size_t)DIM*DIM*2);
  __half* Wf2   = (__half*)alloc((size_t)DIM*DIM*2);
  float* c1root = (float*)alloc(DIM*4);
  float* cvec   = (float*)alloc(DIM*4);
  float* cpool  = (float*)alloc(DIM*4);
  int*   cnt    = (int*)alloc((size_t)N*4);
  int*   csrp   = (int*)alloc((size_t)N*CSTRIDE*4);
  int*   bCur   = (int*)alloc(256*4);
  int    NBUCK  = (N + (1 << BSHIFT) - 1) >> BSHIFT;   // 196
  uint2* spair  = (uint2*)alloc((size_t)NBUCK*MAXBE*8);

  int nG  = (N + 63) / 64;                      // 1563 gemm blocks
  int nCB = (E + 2047) / 2048;                  // 782 bucket blocks
  int q3  = ((nG + 1)/2 > nCB) ? (nG + 1)/2 : nCB;
  int nF  = (N*63 + 2047) / 2048;

  k_wprep<<<16, 256, 0, stream>>>(W1, W2, Wf1, Wf2, bCur);
  k_megaB<<<3*q3, 256, 0, stream>>>(posts, Wf1, xw1u, row, col, E, bCur, spair, N, nG, nCB);
  k_build<<<NBUCK, 256, 0, stream>>>(spair, bCur, csrp, cnt, N);
  k_conv1<<<(N + 3)/4, 256, 0, stream>>>(xw1u, csrp, cnt, b1, rootI, c1h, c1root, N);
  k_small<<<1, 128, 0, stream>>>(posts, W2, c1root, rootI, cvec, cpool);
  k_megaC<<<nG + nF, 256, 0, stream>>>(c1h, Wf2, cvec, cnt, xw2s, cpool,
                                       (float*)d_out, N, nG, nF);
  k_conv2<<<(N + 3)/4, 256, 0, stream>>>(xw2s, csrp, cnt, b2, cpool,
                                         (float*)d_out, N);
}